// Round 2
// baseline (437.735 us; speedup 1.0000x reference)
//
#include <hip/hip_runtime.h>

// Problem constants (from reference):
// B=256, D=8192, S=8, W=4, NSLOTS=2048, STATE_LEN=3
#define BB 256
#define DD 8192
#define SS 8
#define NSLOTS 2048
#define STATE_LEN 3

// Single-launch grid layout (flat, no barriers anywhere):
//   blocks [0, CONV_BLOCKS)            : conv path, gridded by batch.
//       b = bid>>5, dchunk = bid&31  (256 d per chunk)
//   blocks [CONV_BLOCKS, +COPY_BLOCKS) : state copy for un-updated slots.
//       slot = cid/3, chunk = cid%3; 3 chunks x 2048 float4 = 24576 floats/slot
//       mapped-ness resolved per-wave: 64 lanes x int4 covers all 256
//       cache_indices (1 KB, L1-resident), wave-wide __any -> uniform exit.
// Traffic: 64R(x) + 192R(states) + 64W(out) + 192W(new_states) = 512 MiB.
#define CONV_BLOCKS (BB * (DD / 256))       // 8192
#define COPY_CHUNKS 3
#define COPY_BLOCKS (NSLOTS * COPY_CHUNKS)  // 6144

typedef float f4 __attribute__((ext_vector_type(4)));

__global__ __launch_bounds__(256)
void fused_conv_state_kernel(const float* __restrict__ x,
                             const float* __restrict__ weight,
                             const float* __restrict__ conv_states,
                             const int* __restrict__ cache_indices,
                             const int* __restrict__ residual_p,
                             const int* __restrict__ pad_p,
                             float* __restrict__ out,
                             float* __restrict__ out_ns) {
    const int bid = blockIdx.x;
    const int tid = threadIdx.x;

    if (bid >= CONV_BLOCKS) {
        // ---- copy path: un-updated slot states, streamed nontemporally ----
        const int cid = bid - CONV_BLOCKS;
        const int n   = cid / COPY_CHUNKS;
        const int c   = cid - n * COPY_CHUNKS;

        // Per-wave mapped-slot test: lane l holds cache_indices[4l..4l+3].
        {
            const int lane = tid & 63;
            const int4 ci4 = ((const int4*)cache_indices)[lane];
            const int pad = pad_p[0];
            const bool m = (ci4.x == n && ci4.x != pad) ||
                           (ci4.y == n && ci4.y != pad) ||
                           (ci4.z == n && ci4.z != pad) ||
                           (ci4.w == n && ci4.w != pad);
            if (__any(m)) return;            // conv path owns this slot
        }

        const size_t base4 = (size_t)n * (DD * STATE_LEN / 4)   // 6144
                           + (size_t)c * 2048 + tid;
        const f4* __restrict__ src = (const f4*)conv_states;
        f4* __restrict__ dst = (f4*)out_ns;
        f4 v[8];
#pragma unroll
        for (int k = 0; k < 8; ++k)
            v[k] = __builtin_nontemporal_load(src + base4 + k * 256);
#pragma unroll
        for (int k = 0; k < 8; ++k)
            __builtin_nontemporal_store(v[k], dst + base4 + k * 256);
        return;
    }

    // ---- conv path: one batch-row chunk of 256 d ----
    const int b      = bid >> 5;
    const int dchunk = bid & 31;
    const int d      = (dchunk << 8) | tid;

    const int  ci    = cache_indices[b];         // block-uniform
    const bool valid = (ci != pad_p[0]);
    const int  slot  = valid ? ci : 0;           // reference's safe_idx

    const size_t sbase = ((size_t)slot * DD + d) * STATE_LEN;
    const float s0 = __builtin_nontemporal_load(conv_states + sbase);
    const float s1 = __builtin_nontemporal_load(conv_states + sbase + 1);
    const float s2 = __builtin_nontemporal_load(conv_states + sbase + 2);

    const f4* __restrict__ xr = (const f4*)(x + ((size_t)b * DD + d) * SS);
    const f4 x0 = __builtin_nontemporal_load(xr);
    const f4 x1 = __builtin_nontemporal_load(xr + 1);
    const f4 wv = ((const f4*)weight)[d];        // 128 KB, reused -> cached

    const float cat[11] = {s0, s1, s2,
                           x0.x, x0.y, x0.z, x0.w,
                           x1.x, x1.y, x1.z, x1.w};
    float o[8];
#pragma unroll
    for (int s = 0; s < SS; ++s) {
        o[s] = cat[s] * wv.x + cat[s + 1] * wv.y +
               cat[s + 2] * wv.z + cat[s + 3] * wv.w;
    }
    if (residual_p[0]) {
        o[0] += x0.x; o[1] += x0.y; o[2] += x0.z; o[3] += x0.w;
        o[4] += x1.x; o[5] += x1.y; o[6] += x1.z; o[7] += x1.w;
    }

    f4* __restrict__ orow = (f4*)(out + ((size_t)b * DD + d) * SS);
    __builtin_nontemporal_store((f4){o[0], o[1], o[2], o[3]}, orow);
    __builtin_nontemporal_store((f4){o[4], o[5], o[6], o[7]}, orow + 1);

    if (valid) {
        // new state = x[..., 5:8]
        __builtin_nontemporal_store(x1.y, out_ns + sbase);
        __builtin_nontemporal_store(x1.z, out_ns + sbase + 1);
        __builtin_nontemporal_store(x1.w, out_ns + sbase + 2);
    }
}

extern "C" void kernel_launch(void* const* d_in, const int* in_sizes, int n_in,
                              void* d_out, int out_size, void* d_ws, size_t ws_size,
                              hipStream_t stream) {
    const float* x           = (const float*)d_in[0];
    const float* weight      = (const float*)d_in[1];
    const float* conv_states = (const float*)d_in[2];
    const int*   cache_idx   = (const int*)d_in[3];
    const int*   residual_p  = (const int*)d_in[4];
    const int*   pad_p       = (const int*)d_in[5];

    float* out    = (float*)d_out;                 // B*D*S floats
    float* out_ns = out + (size_t)BB * DD * SS;    // NSLOTS*D*STATE_LEN floats

    fused_conv_state_kernel<<<CONV_BLOCKS + COPY_BLOCKS, 256, 0, stream>>>(
        x, weight, conv_states, cache_idx, residual_p, pad_p, out, out_ns);
}